// Round 13
// baseline (278.798 us; speedup 1.0000x reference)
//
#include <hip/hip_runtime.h>

#define NNODES 50000
#define NEDGES 800000
#define ETOT   (NNODES + NEDGES)   // 850000 (edges + self loops)
#define NEG 0.2f
#define BKTS 196                   // coarse buckets of 256 nodes (49999>>8 = 195)
#define P1E 4096                   // edges per phase-1 block
#define NP1 ((ETOT + P1E - 1) / P1E)   // 208

typedef unsigned short ushort_t;
typedef unsigned int uint_t;
typedef __attribute__((ext_vector_type(8))) short short8;   // 8 bf16 (4 VGPRs)
typedef __attribute__((ext_vector_type(4))) float f32x4;    // 4 fp32 acc

__device__ __forceinline__ ushort_t f2bf(float f) {   // RTN bf16
  uint_t u = __float_as_uint(f);
  u += 0x7FFFu + ((u >> 16) & 1u);
  return (ushort_t)(u >> 16);
}
__device__ __forceinline__ float bf2f(ushort_t h) {
  return __uint_as_float((uint_t)h << 16);
}

// ---------------- CSR build: two-level LDS counting sort (atomic-free) ----------------
// pcnt stored TRANSPOSED: pcnt[bucket * NP1 + block] so the per-bucket scan is contiguous.
__global__ __launch_bounds__(256) void coarse_hist(const int* __restrict__ ei,
                                                   int* __restrict__ pcnt) {
  __shared__ int c[BKTS];
  for (int i = threadIdx.x; i < BKTS; i += 256) c[i] = 0;
  __syncthreads();
  int e0 = blockIdx.x * P1E;
#pragma unroll
  for (int t = 0; t < P1E / 256; ++t) {
    int i = e0 + t * 256 + (int)threadIdx.x;
    if (i < ETOT) {
      int dst = (i < NEDGES) ? ei[NEDGES + i] : (i - NEDGES);
      atomicAdd(&c[dst >> 8], 1);
    }
  }
  __syncthreads();
  for (int i = threadIdx.x; i < BKTS; i += 256)
    pcnt[i * NP1 + blockIdx.x] = c[i];
}

// one wave per bucket: wave-prefix over its contiguous 208-int row -> goffArr + total
__global__ __launch_bounds__(64) void coarse_scan(const int* __restrict__ pcnt,
                                                  int* __restrict__ goffArr,
                                                  int* __restrict__ tot) {
  int b = blockIdx.x;
  int lane = threadIdx.x;
  int carry = 0;
  for (int k0 = 0; k0 < NP1; k0 += 64) {
    int k = k0 + lane;
    int v = (k < NP1) ? pcnt[b * NP1 + k] : 0;
    int s = v;
    for (int off = 1; off < 64; off <<= 1) {
      int u = __shfl_up(s, off);
      if (lane >= off) s += u;
    }
    if (k < NP1) goffArr[b * NP1 + k] = carry + s - v;   // exclusive
    carry += __shfl(s, 63);
  }
  if (lane == 0) tot[b] = carry;
}

// tiny: exclusive scan of 196 bucket totals
__global__ __launch_bounds__(256) void bucket_scan(const int* __restrict__ tot,
                                                   int* __restrict__ bucketStart,
                                                   int* __restrict__ rowptr) {
  if (threadIdx.x == 0) {
    int r = 0;
    for (int i = 0; i < BKTS; ++i) { bucketStart[i] = r; r += tot[i]; }
    bucketStart[BKTS] = r;          // == ETOT
    rowptr[NNODES] = ETOT;
  }
}

// phase 1: bin edges by coarse bucket. packed = bucket<<24 | dstLow<<16 | src.
__global__ __launch_bounds__(256) void bin_phase1(const int* __restrict__ ei,
                                                  const int* __restrict__ bucketStart,
                                                  const int* __restrict__ goffArr,
                                                  uint_t* __restrict__ binned) {
  __shared__ int cnt[BKTS], pref[BKTS], fillL[BKTS];
  __shared__ uint_t stage[P1E];
  int e0 = blockIdx.x * P1E;
  for (int i = threadIdx.x; i < BKTS; i += 256) { cnt[i] = 0; fillL[i] = 0; }
  __syncthreads();
  uint_t mypk[P1E / 256];
  int mybkt[P1E / 256];
#pragma unroll
  for (int t = 0; t < P1E / 256; ++t) {
    int i = e0 + t * 256 + (int)threadIdx.x;
    if (i < ETOT) {
      int dst = (i < NEDGES) ? ei[NEDGES + i] : (i - NEDGES);
      int src = (i < NEDGES) ? ei[i] : dst;
      int b = dst >> 8;
      mypk[t] = (uint_t)src | ((uint_t)(dst & 255) << 16) | ((uint_t)b << 24);
      mybkt[t] = b;
      atomicAdd(&cnt[b], 1);
    } else mybkt[t] = -1;
  }
  __syncthreads();
  if (threadIdx.x == 0) {
    int r = 0;
    for (int b = 0; b < BKTS; ++b) { pref[b] = r; r += cnt[b]; }
  }
  __syncthreads();
#pragma unroll
  for (int t = 0; t < P1E / 256; ++t) {
    if (mybkt[t] >= 0) {
      int p = pref[mybkt[t]] + atomicAdd(&fillL[mybkt[t]], 1);
      stage[p] = mypk[t];
    }
  }
  __syncthreads();
  int total = (e0 + P1E <= ETOT) ? P1E : (ETOT - e0);
  for (int j = threadIdx.x; j < total; j += 256) {
    uint_t pk = stage[j];
    int b = pk >> 24;
    binned[bucketStart[b] + goffArr[b * NP1 + blockIdx.x] + (j - pref[b])] = pk;
  }
}

// phase 2: per bucket, fine counting sort over 256 nodes -> rowptr + csrc (all coalesced)
__global__ __launch_bounds__(256) void bin_phase2(const uint_t* __restrict__ binned,
                                                  const int* __restrict__ bucketStart,
                                                  int* __restrict__ rowptr,
                                                  int* __restrict__ csrc) {
  __shared__ int cnt[256], pref[256], fillL[256];
  __shared__ int outS[8192];       // max bucket ~4700; ample
  int b = blockIdx.x;
  int base = bucketStart[b];
  int cntAll = bucketStart[b + 1] - base;
  cnt[threadIdx.x] = 0; fillL[threadIdx.x] = 0;
  __syncthreads();
  for (int j = threadIdx.x; j < cntAll; j += 256)
    atomicAdd(&cnt[(binned[base + j] >> 16) & 255], 1);
  __syncthreads();
  if (threadIdx.x == 0) {
    int r = 0;
    for (int i = 0; i < 256; ++i) { pref[i] = r; r += cnt[i]; }
  }
  __syncthreads();
  int node = b * 256 + (int)threadIdx.x;
  if (node < NNODES) rowptr[node] = base + pref[threadIdx.x];
  for (int j = threadIdx.x; j < cntAll; j += 256) {
    uint_t pk = binned[base + j];
    int d = (pk >> 16) & 255;
    int p = pref[d] + atomicAdd(&fillL[d], 1);
    outS[p] = (int)(pk & 0xFFFF);
  }
  __syncthreads();
  for (int j = threadIdx.x; j < cntAll; j += 256)
    csrc[base + j] = outS[j];
}

// ---------------- W prep: transpose + split-bf16 [n][k] ----------------
__global__ __launch_bounds__(256) void prep_w(const float* __restrict__ Wl1,
                                              const float* __restrict__ Wr1,
                                              ushort_t* __restrict__ WtHi,
                                              ushort_t* __restrict__ WtLo) {
  int k = blockIdx.x;           // 0..127
  int n = threadIdx.x;          // 0..255 (concat col)
  float w = (n < 128) ? Wl1[k * 128 + n] : Wr1[k * 128 + (n - 128)];
  ushort_t h = f2bf(w);
  WtHi[n * 128 + k] = h;
  WtLo[n * 128 + k] = f2bf(w - bf2f(h));
}

// ---------------- GEMM1 via MFMA (split-bf16 = fp32-quality) ----------------
__global__ __launch_bounds__(256) void gemm1_mfma(
    const float* __restrict__ x,
    const ushort_t* __restrict__ WtHi, const ushort_t* __restrict__ WtLo,
    const float* __restrict__ bl1, const float* __restrict__ br1,
    ushort_t* __restrict__ gl1, float* __restrict__ gr1) {
  constexpr int LDA = 132;
  __shared__ ushort_t Ahi[32][LDA];
  __shared__ ushort_t Alo[32][LDA];
  __shared__ float Cs[32][260];       // 256 cols + pad
  int m0 = blockIdx.x * 32;
  int tid = threadIdx.x;
#pragma unroll
  for (int i = 0; i < 4; ++i) {
    int it = i * 256 + tid;
    int row = it >> 5, c4 = it & 31;
    int gm = m0 + row;
    float4 v = (gm < NNODES) ? *(const float4*)&x[(size_t)gm * 128 + 4 * c4]
                             : make_float4(0.f, 0.f, 0.f, 0.f);
    ushort_t h0 = f2bf(v.x), h1 = f2bf(v.y), h2 = f2bf(v.z), h3 = f2bf(v.w);
    ushort_t l0 = f2bf(v.x - bf2f(h0)), l1 = f2bf(v.y - bf2f(h1));
    ushort_t l2 = f2bf(v.z - bf2f(h2)), l3 = f2bf(v.w - bf2f(h3));
    uint2 ph, pl;
    ph.x = (uint_t)h0 | ((uint_t)h1 << 16); ph.y = (uint_t)h2 | ((uint_t)h3 << 16);
    pl.x = (uint_t)l0 | ((uint_t)l1 << 16); pl.y = (uint_t)l2 | ((uint_t)l3 << 16);
    *(uint2*)&Ahi[row][4 * c4] = ph;
    *(uint2*)&Alo[row][4 * c4] = pl;
  }
  __syncthreads();
  int wave = tid >> 6, lane = tid & 63;
  int quad = lane >> 4, nl = lane & 15;
  int nb = wave * 64;
  f32x4 acc[2][4];
#pragma unroll
  for (int tm = 0; tm < 2; ++tm)
#pragma unroll
    for (int tn = 0; tn < 4; ++tn) acc[tm][tn] = (f32x4){0.f, 0.f, 0.f, 0.f};

#pragma unroll
  for (int kc = 0; kc < 4; ++kc) {
    int klane = kc * 32 + quad * 8;
    short8 ah[2], al[2], bh[4], bl[4];
#pragma unroll
    for (int tm = 0; tm < 2; ++tm) {
      ah[tm] = *(const short8*)&Ahi[16 * tm + nl][klane];
      al[tm] = *(const short8*)&Alo[16 * tm + nl][klane];
    }
#pragma unroll
    for (int tn = 0; tn < 4; ++tn) {
      size_t wo = (size_t)(nb + 16 * tn + nl) * 128 + klane;
      bh[tn] = *(const short8*)&WtHi[wo];
      bl[tn] = *(const short8*)&WtLo[wo];
    }
#pragma unroll
    for (int tm = 0; tm < 2; ++tm)
#pragma unroll
      for (int tn = 0; tn < 4; ++tn) {
        acc[tm][tn] = __builtin_amdgcn_mfma_f32_16x16x32_bf16(ah[tm], bh[tn], acc[tm][tn], 0, 0, 0);
        acc[tm][tn] = __builtin_amdgcn_mfma_f32_16x16x32_bf16(ah[tm], bl[tn], acc[tm][tn], 0, 0, 0);
        acc[tm][tn] = __builtin_amdgcn_mfma_f32_16x16x32_bf16(al[tm], bh[tn], acc[tm][tn], 0, 0, 0);
      }
  }
  float bb[4];
#pragma unroll
  for (int tn = 0; tn < 4; ++tn) {
    int n = nb + 16 * tn + nl;
    bb[tn] = (n < 128) ? bl1[n] : br1[n - 128];
  }
#pragma unroll
  for (int tm = 0; tm < 2; ++tm)
#pragma unroll
    for (int tn = 0; tn < 4; ++tn)
#pragma unroll
      for (int r = 0; r < 4; ++r)
        Cs[16 * tm + 4 * quad + r][nb + 16 * tn + nl] = acc[tm][tn][r] + bb[tn];
  __syncthreads();
#pragma unroll
  for (int i = 0; i < 2; ++i) {
    int it = i * 256 + tid;
    int row = it >> 4, oc = (it & 15) * 8;
    int gm = m0 + row;
    if (gm < NNODES) {
      uint4 pk;
      pk.x = (uint_t)f2bf(Cs[row][oc + 0]) | ((uint_t)f2bf(Cs[row][oc + 1]) << 16);
      pk.y = (uint_t)f2bf(Cs[row][oc + 2]) | ((uint_t)f2bf(Cs[row][oc + 3]) << 16);
      pk.z = (uint_t)f2bf(Cs[row][oc + 4]) | ((uint_t)f2bf(Cs[row][oc + 5]) << 16);
      pk.w = (uint_t)f2bf(Cs[row][oc + 6]) | ((uint_t)f2bf(Cs[row][oc + 7]) << 16);
      *(uint4*)&gl1[(size_t)gm * 128 + oc] = pk;
    }
  }
#pragma unroll
  for (int i = 0; i < 4; ++i) {
    int it = i * 256 + tid;
    int row = it >> 5, oc4 = (it & 31) * 4;
    int gm = m0 + row;
    if (gm < NNODES)
      *(float4*)&gr1[(size_t)gm * 128 + oc4] = *(const float4*)&Cs[row][128 + oc4];
  }
}

// ---------------- register-tiled fp32 GEMM (layer 2) ----------------
template<int BM, int BN, int MCOLS, bool BF16G1>
__global__ __launch_bounds__((BM / 8) * (BN / 8))
void gemm_tile(const float* __restrict__ A,
               const float* __restrict__ W1, const float* __restrict__ b1,
               const float* __restrict__ W2, const float* __restrict__ b2,
               void* __restrict__ G1v, float* __restrict__ G2) {
  constexpr int K = 128, KC = 32;
  constexpr int NT = (BM / 8) * (BN / 8);
  constexpr int LDA = BM + 4;
  __shared__ float AsT[KC][LDA];           // A transposed: [k][m]
  __shared__ float Ws[KC][BN];             // [k][n]
  int row0 = blockIdx.x * BM;
  int n0   = blockIdx.y * BN;
  int tid = threadIdx.x;
  int tx = tid % (BN / 8), ty = tid / (BN / 8);
  float acc[8][8];
#pragma unroll
  for (int i = 0; i < 8; ++i)
#pragma unroll
    for (int j = 0; j < 8; ++j) acc[i][j] = 0.f;

  for (int kc = 0; kc < K; kc += KC) {
#pragma unroll
    for (int item = tid; item < BM * (KC / 4); item += NT) {
      int r = item >> 3, f4 = item & 7;
      int grow = row0 + r;
      float4 v = (grow < NNODES) ? *(const float4*)&A[(size_t)grow * K + kc + 4 * f4]
                                 : make_float4(0.f, 0.f, 0.f, 0.f);
      AsT[4 * f4 + 0][r] = v.x;
      AsT[4 * f4 + 1][r] = v.y;
      AsT[4 * f4 + 2][r] = v.z;
      AsT[4 * f4 + 3][r] = v.w;
    }
#pragma unroll
    for (int item = tid; item < KC * (BN / 4); item += NT) {
      int k = item / (BN / 4), c4 = item % (BN / 4);
      int ccat = n0 + 4 * c4;
      const float* src = (ccat < MCOLS)
          ? &W1[(size_t)(kc + k) * MCOLS + ccat]
          : &W2[(size_t)(kc + k) * MCOLS + ccat - MCOLS];
      *(float4*)&Ws[k][4 * c4] = *(const float4*)src;
    }
    __syncthreads();
#pragma unroll 8
    for (int k = 0; k < KC; ++k) {
      float4 a0 = *(const float4*)&AsT[k][4 * ty];
      float4 a1 = *(const float4*)&AsT[k][BM / 2 + 4 * ty];
      float4 w0 = *(const float4*)&Ws[k][4 * tx];
      float4 w1 = *(const float4*)&Ws[k][BN / 2 + 4 * tx];
      float av[8] = {a0.x, a0.y, a0.z, a0.w, a1.x, a1.y, a1.z, a1.w};
      float wv[8] = {w0.x, w0.y, w0.z, w0.w, w1.x, w1.y, w1.z, w1.w};
#pragma unroll
      for (int i = 0; i < 8; ++i)
#pragma unroll
        for (int j = 0; j < 8; ++j) acc[i][j] = fmaf(av[i], wv[j], acc[i][j]);
    }
    __syncthreads();
  }
#pragma unroll
  for (int i = 0; i < 8; ++i) {
    int row = row0 + (i < 4 ? 4 * ty + i : BM / 2 + 4 * ty + (i - 4));
    if (row >= NNODES) continue;
#pragma unroll
    for (int jj = 0; jj < 2; ++jj) {
      int ccat = n0 + (jj == 0 ? 4 * tx : BN / 2 + 4 * tx);
      float4 o = make_float4(acc[i][4 * jj + 0], acc[i][4 * jj + 1],
                             acc[i][4 * jj + 2], acc[i][4 * jj + 3]);
      if (ccat < MCOLS) {
        float4 bb = *(const float4*)&b1[ccat];
        o.x += bb.x; o.y += bb.y; o.z += bb.z; o.w += bb.w;
        if (BF16G1) {
          uint2 pk;
          pk.x = (uint_t)f2bf(o.x) | ((uint_t)f2bf(o.y) << 16);
          pk.y = (uint_t)f2bf(o.z) | ((uint_t)f2bf(o.w) << 16);
          *(uint2*)((ushort_t*)G1v + (size_t)row * MCOLS + ccat) = pk;
        } else {
          *(float4*)((float*)G1v + (size_t)row * MCOLS + ccat) = o;
        }
      } else {
        float4 bb = *(const float4*)&b2[ccat - MCOLS];
        o.x += bb.x; o.y += bb.y; o.z += bb.z; o.w += bb.w;
        *(float4*)&G2[(size_t)row * MCOLS + ccat - MCOLS] = o;
      }
    }
  }
}

// ---------------- layer 1: wave/node, 16 lanes/edge, branchless full blocks + tail ----------------
__global__ __launch_bounds__(256) void gat1_edge(const int* __restrict__ rowptr,
                          const int* __restrict__ csrc,
                          const ushort_t* __restrict__ glb,    // bf16 table [N][128]
                          const float* __restrict__ gr,
                          const float* __restrict__ att, const float* __restrict__ bias,
                          float* __restrict__ hout) {
  int node = blockIdx.x * 4 + (threadIdx.x >> 6);
  if (node >= NNODES) return;
  int lane = threadIdx.x & 63;
  int eslot = lane >> 4;        // 4 edge slots
  int q = lane & 15;            // 16 lanes per edge; lane covers 8 channels
  int c8 = q * 8;               // head = q>>2
  float4 av0 = *(const float4*)(att + c8);
  float4 av1 = *(const float4*)(att + c8 + 4);
  float4 gr0 = *(const float4*)(gr + (size_t)node * 128 + c8);
  float4 gr1v = *(const float4*)(gr + (size_t)node * 128 + c8 + 4);
  int start = rowptr[node], end = rowptr[node + 1];
  float denom = 0.f;
  float4 A0 = make_float4(0.f, 0.f, 0.f, 0.f);
  float4 A1 = make_float4(0.f, 0.f, 0.f, 0.f);

  auto body = [&](int s, bool pv) {
    uint4 up = *(const uint4*)(glb + (size_t)s * 128 + c8);  // 8 bf16 channels
    float4 g0, g1;
    g0.x = __uint_as_float(up.x << 16);
    g0.y = __uint_as_float(up.x & 0xffff0000u);
    g0.z = __uint_as_float(up.y << 16);
    g0.w = __uint_as_float(up.y & 0xffff0000u);
    g1.x = __uint_as_float(up.z << 16);
    g1.y = __uint_as_float(up.z & 0xffff0000u);
    g1.z = __uint_as_float(up.w << 16);
    g1.w = __uint_as_float(up.w & 0xffff0000u);
    float t, v;
    t = g0.x + gr0.x; t = fmaxf(t, NEG * t); v = av0.x * t;
    t = g0.y + gr0.y; t = fmaxf(t, NEG * t); v = fmaf(av0.y, t, v);
    t = g0.z + gr0.z; t = fmaxf(t, NEG * t); v = fmaf(av0.z, t, v);
    t = g0.w + gr0.w; t = fmaxf(t, NEG * t); v = fmaf(av0.w, t, v);
    t = g1.x + gr1v.x; t = fmaxf(t, NEG * t); v = fmaf(av1.x, t, v);
    t = g1.y + gr1v.y; t = fmaxf(t, NEG * t); v = fmaf(av1.y, t, v);
    t = g1.z + gr1v.z; t = fmaxf(t, NEG * t); v = fmaf(av1.z, t, v);
    t = g1.w + gr1v.w; t = fmaxf(t, NEG * t); v = fmaf(av1.w, t, v);
    v += __shfl_xor(v, 1); v += __shfl_xor(v, 2);   // e[head] over 4 lanes (32 ch)
    float ex = pv ? __expf(v) : 0.f;                // max-free softmax (|e| bounded)
    denom += ex;
    A0.x = fmaf(ex, g0.x, A0.x); A0.y = fmaf(ex, g0.y, A0.y);
    A0.z = fmaf(ex, g0.z, A0.z); A0.w = fmaf(ex, g0.w, A0.w);
    A1.x = fmaf(ex, g1.x, A1.x); A1.y = fmaf(ex, g1.y, A1.y);
    A1.z = fmaf(ex, g1.z, A1.z); A1.w = fmaf(ex, g1.w, A1.w);
  };

  int b = start;
  int sidx = (b + lane < end) ? csrc[b + lane] : 0;
  for (; b + 64 <= end; b += 64) {           // full blocks: branchless
    int sn = (b + 64 + lane < end) ? csrc[b + 64 + lane] : 0;   // prefetch next batch
#pragma unroll 2
    for (int j = 0; j < 64; j += 4)
      body(__shfl(sidx, j + eslot), true);
    sidx = sn;
  }
  int nb = end - b;                           // tail (< 64)
  for (int j = 0; j < nb; j += 4)
    body(__shfl(sidx, j + eslot), (j + eslot) < nb);

  denom += __shfl_xor(denom, 16); denom += __shfl_xor(denom, 32);
  A0.x += __shfl_xor(A0.x, 16); A0.x += __shfl_xor(A0.x, 32);
  A0.y += __shfl_xor(A0.y, 16); A0.y += __shfl_xor(A0.y, 32);
  A0.z += __shfl_xor(A0.z, 16); A0.z += __shfl_xor(A0.z, 32);
  A0.w += __shfl_xor(A0.w, 16); A0.w += __shfl_xor(A0.w, 32);
  A1.x += __shfl_xor(A1.x, 16); A1.x += __shfl_xor(A1.x, 32);
  A1.y += __shfl_xor(A1.y, 16); A1.y += __shfl_xor(A1.y, 32);
  A1.z += __shfl_xor(A1.z, 16); A1.z += __shfl_xor(A1.z, 32);
  A1.w += __shfl_xor(A1.w, 16); A1.w += __shfl_xor(A1.w, 32);
  float inv = 1.f / denom;
  if (eslot == 0) {
    float4 bv = *(const float4*)(bias + c8);
    float4 o;
    o.x = A0.x * inv + bv.x; o.y = A0.y * inv + bv.y;
    o.z = A0.z * inv + bv.z; o.w = A0.w * inv + bv.w;
    o.x = o.x > 0.f ? o.x : __expf(o.x) - 1.f;
    o.y = o.y > 0.f ? o.y : __expf(o.y) - 1.f;
    o.z = o.z > 0.f ? o.z : __expf(o.z) - 1.f;
    o.w = o.w > 0.f ? o.w : __expf(o.w) - 1.f;
    *(float4*)(hout + (size_t)node * 128 + c8) = o;
  } else if (eslot == 1) {
    float4 bv = *(const float4*)(bias + c8 + 4);
    float4 o;
    o.x = A1.x * inv + bv.x; o.y = A1.y * inv + bv.y;
    o.z = A1.z * inv + bv.z; o.w = A1.w * inv + bv.w;
    o.x = o.x > 0.f ? o.x : __expf(o.x) - 1.f;
    o.y = o.y > 0.f ? o.y : __expf(o.y) - 1.f;
    o.z = o.z > 0.f ? o.z : __expf(o.z) - 1.f;
    o.w = o.w > 0.f ? o.w : __expf(o.w) - 1.f;
    *(float4*)(hout + (size_t)node * 128 + c8 + 4) = o;
  }
}

// ---------------- layer 2: wave/node, 8 lanes/edge, branchless full blocks + tail ----------------
__global__ __launch_bounds__(256) void gat2_edge(const int* __restrict__ rowptr,
                          const int* __restrict__ csrc,
                          const float* __restrict__ gl, const float* __restrict__ gr,
                          const float* __restrict__ att, const float* __restrict__ bias,
                          float* __restrict__ out) {
  int node = blockIdx.x * 4 + (threadIdx.x >> 6);
  if (node >= NNODES) return;
  int lane = threadIdx.x & 63;
  int eslot = lane >> 3;        // 8 edge slots
  int q = lane & 7;             // 8 lanes per edge, 4 ch each
  int c4 = q * 4;
  float4 avc = *(const float4*)(att + c4);
  float4 grd = *(const float4*)(gr + (size_t)node * 32 + c4);
  int start = rowptr[node], end = rowptr[node + 1];
  float denom = 0.f;
  float4 A = make_float4(0.f, 0.f, 0.f, 0.f);

  auto body = [&](int s, bool pv) {
    float4 g = *(const float4*)(gl + (size_t)s * 32 + c4);
    float t, v;
    t = g.x + grd.x; t = fmaxf(t, NEG * t); v = avc.x * t;
    t = g.y + grd.y; t = fmaxf(t, NEG * t); v = fmaf(avc.y, t, v);
    t = g.z + grd.z; t = fmaxf(t, NEG * t); v = fmaf(avc.z, t, v);
    t = g.w + grd.w; t = fmaxf(t, NEG * t); v = fmaf(avc.w, t, v);
    v += __shfl_xor(v, 1); v += __shfl_xor(v, 2); v += __shfl_xor(v, 4);
    float ex = pv ? __expf(v) : 0.f;
    denom += ex;
    A.x = fmaf(ex, g.x, A.x); A.y = fmaf(ex, g.y, A.y);
    A.z = fmaf(ex, g.z, A.z); A.w = fmaf(ex, g.w, A.w);
  };

  int b = start;
  int sidx = (b + lane < end) ? csrc[b + lane] : 0;
  for (; b + 64 <= end; b += 64) {
    int sn = (b + 64 + lane < end) ? csrc[b + 64 + lane] : 0;
#pragma unroll 2
    for (int j = 0; j < 64; j += 8)
      body(__shfl(sidx, j + eslot), true);
    sidx = sn;
  }
  int nb = end - b;
  for (int j = 0; j < nb; j += 8)
    body(__shfl(sidx, j + eslot), (j + eslot) < nb);

  denom += __shfl_xor(denom, 8); denom += __shfl_xor(denom, 16); denom += __shfl_xor(denom, 32);
  A.x += __shfl_xor(A.x, 8); A.x += __shfl_xor(A.x, 16); A.x += __shfl_xor(A.x, 32);
  A.y += __shfl_xor(A.y, 8); A.y += __shfl_xor(A.y, 16); A.y += __shfl_xor(A.y, 32);
  A.z += __shfl_xor(A.z, 8); A.z += __shfl_xor(A.z, 16); A.z += __shfl_xor(A.z, 32);
  A.w += __shfl_xor(A.w, 8); A.w += __shfl_xor(A.w, 16); A.w += __shfl_xor(A.w, 32);
  if (eslot == 0) {
    float4 bv = *(const float4*)(bias + c4);
    float inv = 1.f / denom;
    float4 o;
    o.x = A.x * inv + bv.x; o.y = A.y * inv + bv.y;
    o.z = A.z * inv + bv.z; o.w = A.w * inv + bv.w;
    *(float4*)(out + (size_t)node * 32 + c4) = o;
  }
}

extern "C" void kernel_launch(void* const* d_in, const int* in_sizes, int n_in,
                              void* d_out, int out_size, void* d_ws, size_t ws_size,
                              hipStream_t stream) {
  const float* x     = (const float*)d_in[0];
  const int*   ei    = (const int*)  d_in[1];
  const float* Wl1   = (const float*)d_in[2];
  const float* bl1   = (const float*)d_in[3];
  const float* Wr1   = (const float*)d_in[4];
  const float* br1   = (const float*)d_in[5];
  const float* att1  = (const float*)d_in[6];
  const float* bias1 = (const float*)d_in[7];
  const float* Wl2   = (const float*)d_in[8];
  const float* bl2   = (const float*)d_in[9];
  const float* Wr2   = (const float*)d_in[10];
  const float* br2   = (const float*)d_in[11];
  const float* att2  = (const float*)d_in[12];
  const float* bias2 = (const float*)d_in[13];
  float* out = (float*)d_out;

  char* w = (char*)d_ws;
  auto carve = [&](size_t bytes) {
    char* p = w;
    w += (bytes + 255) & ~(size_t)255;
    return p;
  };
  ushort_t* gl1 = (ushort_t*)carve((size_t)NNODES * 128 * 2);   // bf16 gather table
  float* gr1 = (float*)carve((size_t)NNODES * 128 * 4);
  float* h   = (float*)carve((size_t)NNODES * 128 * 4);
  float* gl2 = (float*)carve((size_t)NNODES * 32 * 4);
  float* gr2 = (float*)carve((size_t)NNODES * 32 * 4);
  ushort_t* WtHi = (ushort_t*)carve((size_t)256 * 128 * 2);
  ushort_t* WtLo = (ushort_t*)carve((size_t)256 * 128 * 2);
  int* pcnt    = (int*)carve((size_t)NP1 * BKTS * 4);
  int* goffArr = (int*)carve((size_t)NP1 * BKTS * 4);
  int* tot     = (int*)carve((size_t)BKTS * 4);
  int* bucketStart = (int*)carve((size_t)(BKTS + 1) * 4);
  int* rowptr = (int*)carve((size_t)(NNODES + 1) * 4);
  uint_t* binned = (uint_t*)carve((size_t)ETOT * 4);
  int* csrc = (int*)carve((size_t)ETOT * 4);

  prep_w<<<128, 256, 0, stream>>>(Wl1, Wr1, WtHi, WtLo);
  coarse_hist<<<NP1, 256, 0, stream>>>(ei, pcnt);
  coarse_scan<<<BKTS, 64, 0, stream>>>(pcnt, goffArr, tot);
  bucket_scan<<<1, 256, 0, stream>>>(tot, bucketStart, rowptr);
  bin_phase1<<<NP1, 256, 0, stream>>>(ei, bucketStart, goffArr, binned);
  bin_phase2<<<BKTS, 256, 0, stream>>>(binned, bucketStart, rowptr, csrc);

  gemm1_mfma<<<(NNODES + 31) / 32, 256, 0, stream>>>(x, WtHi, WtLo, bl1, br1, gl1, gr1);
  gat1_edge<<<(NNODES + 3) / 4, 256, 0, stream>>>(rowptr, csrc, gl1, gr1, att1, bias1, h);
  gemm_tile<128, 64, 32, false><<<dim3((NNODES + 127) / 128, 1), 128, 0, stream>>>(
      h, Wl2, bl2, Wr2, br2, (void*)gl2, gr2);
  gat2_edge<<<(NNODES + 3) / 4, 256, 0, stream>>>(rowptr, csrc, gl2, gr2, att2, bias2, out);
}

// Round 14
// 272.669 us; speedup vs baseline: 1.0225x; 1.0225x over previous
//
#include <hip/hip_runtime.h>

#define NNODES 50000
#define NEDGES 800000
#define ETOT   (NNODES + NEDGES)   // 850000 (edges + self loops)
#define NEG 0.2f
#define BKTS 196                   // coarse buckets of 256 nodes (49999>>8 = 195)
#define P1E 4096                   // edges per phase-1 block
#define NP1 ((ETOT + P1E - 1) / P1E)   // 208

typedef unsigned short ushort_t;
typedef unsigned int uint_t;
typedef __attribute__((ext_vector_type(8))) short short8;   // 8 bf16 (4 VGPRs)
typedef __attribute__((ext_vector_type(4))) float f32x4;    // 4 fp32 acc

__device__ __forceinline__ ushort_t f2bf(float f) {   // RTN bf16
  uint_t u = __float_as_uint(f);
  u += 0x7FFFu + ((u >> 16) & 1u);
  return (ushort_t)(u >> 16);
}
__device__ __forceinline__ float bf2f(ushort_t h) {
  return __uint_as_float((uint_t)h << 16);
}

// ---------------- CSR build: two-level LDS counting sort (atomic-free) ----------------
// pcnt stored TRANSPOSED: pcnt[bucket * NP1 + block] so the per-bucket scan is contiguous.
__global__ __launch_bounds__(256) void coarse_hist(const int* __restrict__ ei,
                                                   int* __restrict__ pcnt) {
  __shared__ int c[BKTS];
  for (int i = threadIdx.x; i < BKTS; i += 256) c[i] = 0;
  __syncthreads();
  int e0 = blockIdx.x * P1E;
#pragma unroll
  for (int t = 0; t < P1E / 256; ++t) {
    int i = e0 + t * 256 + (int)threadIdx.x;
    if (i < ETOT) {
      int dst = (i < NEDGES) ? ei[NEDGES + i] : (i - NEDGES);
      atomicAdd(&c[dst >> 8], 1);
    }
  }
  __syncthreads();
  for (int i = threadIdx.x; i < BKTS; i += 256)
    pcnt[i * NP1 + blockIdx.x] = c[i];
}

// one wave per bucket: wave-prefix over its contiguous 208-int row -> goffArr + total
__global__ __launch_bounds__(64) void coarse_scan(const int* __restrict__ pcnt,
                                                  int* __restrict__ goffArr,
                                                  int* __restrict__ tot) {
  int b = blockIdx.x;
  int lane = threadIdx.x;
  int carry = 0;
  for (int k0 = 0; k0 < NP1; k0 += 64) {
    int k = k0 + lane;
    int v = (k < NP1) ? pcnt[b * NP1 + k] : 0;
    int s = v;
    for (int off = 1; off < 64; off <<= 1) {
      int u = __shfl_up(s, off);
      if (lane >= off) s += u;
    }
    if (k < NP1) goffArr[b * NP1 + k] = carry + s - v;   // exclusive
    carry += __shfl(s, 63);
  }
  if (lane == 0) tot[b] = carry;
}

// tiny: exclusive scan of 196 bucket totals
__global__ __launch_bounds__(256) void bucket_scan(const int* __restrict__ tot,
                                                   int* __restrict__ bucketStart,
                                                   int* __restrict__ rowptr) {
  if (threadIdx.x == 0) {
    int r = 0;
    for (int i = 0; i < BKTS; ++i) { bucketStart[i] = r; r += tot[i]; }
    bucketStart[BKTS] = r;          // == ETOT
    rowptr[NNODES] = ETOT;
  }
}

// phase 1: bin edges by coarse bucket. packed = bucket<<24 | dstLow<<16 | src.
__global__ __launch_bounds__(256) void bin_phase1(const int* __restrict__ ei,
                                                  const int* __restrict__ bucketStart,
                                                  const int* __restrict__ goffArr,
                                                  uint_t* __restrict__ binned) {
  __shared__ int cnt[BKTS], pref[BKTS], fillL[BKTS];
  __shared__ uint_t stage[P1E];
  int e0 = blockIdx.x * P1E;
  for (int i = threadIdx.x; i < BKTS; i += 256) { cnt[i] = 0; fillL[i] = 0; }
  __syncthreads();
  uint_t mypk[P1E / 256];
  int mybkt[P1E / 256];
#pragma unroll
  for (int t = 0; t < P1E / 256; ++t) {
    int i = e0 + t * 256 + (int)threadIdx.x;
    if (i < ETOT) {
      int dst = (i < NEDGES) ? ei[NEDGES + i] : (i - NEDGES);
      int src = (i < NEDGES) ? ei[i] : dst;
      int b = dst >> 8;
      mypk[t] = (uint_t)src | ((uint_t)(dst & 255) << 16) | ((uint_t)b << 24);
      mybkt[t] = b;
      atomicAdd(&cnt[b], 1);
    } else mybkt[t] = -1;
  }
  __syncthreads();
  if (threadIdx.x == 0) {
    int r = 0;
    for (int b = 0; b < BKTS; ++b) { pref[b] = r; r += cnt[b]; }
  }
  __syncthreads();
#pragma unroll
  for (int t = 0; t < P1E / 256; ++t) {
    if (mybkt[t] >= 0) {
      int p = pref[mybkt[t]] + atomicAdd(&fillL[mybkt[t]], 1);
      stage[p] = mypk[t];
    }
  }
  __syncthreads();
  int total = (e0 + P1E <= ETOT) ? P1E : (ETOT - e0);
  for (int j = threadIdx.x; j < total; j += 256) {
    uint_t pk = stage[j];
    int b = pk >> 24;
    binned[bucketStart[b] + goffArr[b * NP1 + blockIdx.x] + (j - pref[b])] = pk;
  }
}

// phase 2: per bucket, fine counting sort over 256 nodes -> rowptr + csrc (all coalesced)
__global__ __launch_bounds__(256) void bin_phase2(const uint_t* __restrict__ binned,
                                                  const int* __restrict__ bucketStart,
                                                  int* __restrict__ rowptr,
                                                  int* __restrict__ csrc) {
  __shared__ int cnt[256], pref[256], fillL[256];
  __shared__ int outS[8192];       // max bucket ~4700; ample
  int b = blockIdx.x;
  int base = bucketStart[b];
  int cntAll = bucketStart[b + 1] - base;
  cnt[threadIdx.x] = 0; fillL[threadIdx.x] = 0;
  __syncthreads();
  for (int j = threadIdx.x; j < cntAll; j += 256)
    atomicAdd(&cnt[(binned[base + j] >> 16) & 255], 1);
  __syncthreads();
  if (threadIdx.x == 0) {
    int r = 0;
    for (int i = 0; i < 256; ++i) { pref[i] = r; r += cnt[i]; }
  }
  __syncthreads();
  int node = b * 256 + (int)threadIdx.x;
  if (node < NNODES) rowptr[node] = base + pref[threadIdx.x];
  for (int j = threadIdx.x; j < cntAll; j += 256) {
    uint_t pk = binned[base + j];
    int d = (pk >> 16) & 255;
    int p = pref[d] + atomicAdd(&fillL[d], 1);
    outS[p] = (int)(pk & 0xFFFF);
  }
  __syncthreads();
  for (int j = threadIdx.x; j < cntAll; j += 256)
    csrc[base + j] = outS[j];
}

// ---------------- W prep: transpose + split-bf16 [n][k] ----------------
__global__ __launch_bounds__(256) void prep_w(const float* __restrict__ Wl1,
                                              const float* __restrict__ Wr1,
                                              ushort_t* __restrict__ WtHi,
                                              ushort_t* __restrict__ WtLo) {
  int k = blockIdx.x;           // 0..127
  int n = threadIdx.x;          // 0..255 (concat col)
  float w = (n < 128) ? Wl1[k * 128 + n] : Wr1[k * 128 + (n - 128)];
  ushort_t h = f2bf(w);
  WtHi[n * 128 + k] = h;
  WtLo[n * 128 + k] = f2bf(w - bf2f(h));
}

// ---------------- GEMM1 via MFMA (split-bf16 = fp32-quality) ----------------
// LDS union: Cs overlays Ahi/Alo (Cs only live post-MFMA) -> 33 KB block, 4 blocks/CU.
__global__ __launch_bounds__(256) void gemm1_mfma(
    const float* __restrict__ x,
    const ushort_t* __restrict__ WtHi, const ushort_t* __restrict__ WtLo,
    const float* __restrict__ bl1, const float* __restrict__ br1,
    ushort_t* __restrict__ gl1, float* __restrict__ gr1) {
  constexpr int LDA = 132;
  __shared__ __align__(16) char smem[32 * 260 * 4];   // 33280 B (>= 2*32*132*2 = 16896)
  ushort_t (*Ahi)[LDA] = (ushort_t(*)[LDA])smem;
  ushort_t (*Alo)[LDA] = (ushort_t(*)[LDA])(smem + 32 * LDA * 2);
  float (*Cs)[260] = (float(*)[260])smem;
  int m0 = blockIdx.x * 32;
  int tid = threadIdx.x;
#pragma unroll
  for (int i = 0; i < 4; ++i) {
    int it = i * 256 + tid;
    int row = it >> 5, c4 = it & 31;
    int gm = m0 + row;
    float4 v = (gm < NNODES) ? *(const float4*)&x[(size_t)gm * 128 + 4 * c4]
                             : make_float4(0.f, 0.f, 0.f, 0.f);
    ushort_t h0 = f2bf(v.x), h1 = f2bf(v.y), h2 = f2bf(v.z), h3 = f2bf(v.w);
    ushort_t l0 = f2bf(v.x - bf2f(h0)), l1 = f2bf(v.y - bf2f(h1));
    ushort_t l2 = f2bf(v.z - bf2f(h2)), l3 = f2bf(v.w - bf2f(h3));
    uint2 ph, pl;
    ph.x = (uint_t)h0 | ((uint_t)h1 << 16); ph.y = (uint_t)h2 | ((uint_t)h3 << 16);
    pl.x = (uint_t)l0 | ((uint_t)l1 << 16); pl.y = (uint_t)l2 | ((uint_t)l3 << 16);
    *(uint2*)&Ahi[row][4 * c4] = ph;
    *(uint2*)&Alo[row][4 * c4] = pl;
  }
  __syncthreads();
  int wave = tid >> 6, lane = tid & 63;
  int quad = lane >> 4, nl = lane & 15;
  int nb = wave * 64;
  f32x4 acc[2][4];
#pragma unroll
  for (int tm = 0; tm < 2; ++tm)
#pragma unroll
    for (int tn = 0; tn < 4; ++tn) acc[tm][tn] = (f32x4){0.f, 0.f, 0.f, 0.f};

#pragma unroll
  for (int kc = 0; kc < 4; ++kc) {
    int klane = kc * 32 + quad * 8;
    short8 ah[2], al[2], bh[4], bl[4];
#pragma unroll
    for (int tm = 0; tm < 2; ++tm) {
      ah[tm] = *(const short8*)&Ahi[16 * tm + nl][klane];
      al[tm] = *(const short8*)&Alo[16 * tm + nl][klane];
    }
#pragma unroll
    for (int tn = 0; tn < 4; ++tn) {
      size_t wo = (size_t)(nb + 16 * tn + nl) * 128 + klane;
      bh[tn] = *(const short8*)&WtHi[wo];
      bl[tn] = *(const short8*)&WtLo[wo];
    }
#pragma unroll
    for (int tm = 0; tm < 2; ++tm)
#pragma unroll
      for (int tn = 0; tn < 4; ++tn) {
        acc[tm][tn] = __builtin_amdgcn_mfma_f32_16x16x32_bf16(ah[tm], bh[tn], acc[tm][tn], 0, 0, 0);
        acc[tm][tn] = __builtin_amdgcn_mfma_f32_16x16x32_bf16(ah[tm], bl[tn], acc[tm][tn], 0, 0, 0);
        acc[tm][tn] = __builtin_amdgcn_mfma_f32_16x16x32_bf16(al[tm], bh[tn], acc[tm][tn], 0, 0, 0);
      }
  }
  float bb[4];
#pragma unroll
  for (int tn = 0; tn < 4; ++tn) {
    int n = nb + 16 * tn + nl;
    bb[tn] = (n < 128) ? bl1[n] : br1[n - 128];
  }
  __syncthreads();   // all A-tile reads done before Cs overlays the same LDS
#pragma unroll
  for (int tm = 0; tm < 2; ++tm)
#pragma unroll
    for (int tn = 0; tn < 4; ++tn)
#pragma unroll
      for (int r = 0; r < 4; ++r)
        Cs[16 * tm + 4 * quad + r][nb + 16 * tn + nl] = acc[tm][tn][r] + bb[tn];
  __syncthreads();
#pragma unroll
  for (int i = 0; i < 2; ++i) {
    int it = i * 256 + tid;
    int row = it >> 4, oc = (it & 15) * 8;
    int gm = m0 + row;
    if (gm < NNODES) {
      uint4 pk;
      pk.x = (uint_t)f2bf(Cs[row][oc + 0]) | ((uint_t)f2bf(Cs[row][oc + 1]) << 16);
      pk.y = (uint_t)f2bf(Cs[row][oc + 2]) | ((uint_t)f2bf(Cs[row][oc + 3]) << 16);
      pk.z = (uint_t)f2bf(Cs[row][oc + 4]) | ((uint_t)f2bf(Cs[row][oc + 5]) << 16);
      pk.w = (uint_t)f2bf(Cs[row][oc + 6]) | ((uint_t)f2bf(Cs[row][oc + 7]) << 16);
      *(uint4*)&gl1[(size_t)gm * 128 + oc] = pk;
    }
  }
#pragma unroll
  for (int i = 0; i < 4; ++i) {
    int it = i * 256 + tid;
    int row = it >> 5, oc4 = (it & 31) * 4;
    int gm = m0 + row;
    if (gm < NNODES)
      *(float4*)&gr1[(size_t)gm * 128 + oc4] = *(const float4*)&Cs[row][128 + oc4];
  }
}

// ---------------- register-tiled fp32 GEMM (layer 2) ----------------
template<int BM, int BN, int MCOLS, bool BF16G1>
__global__ __launch_bounds__((BM / 8) * (BN / 8))
void gemm_tile(const float* __restrict__ A,
               const float* __restrict__ W1, const float* __restrict__ b1,
               const float* __restrict__ W2, const float* __restrict__ b2,
               void* __restrict__ G1v, float* __restrict__ G2) {
  constexpr int K = 128, KC = 32;
  constexpr int NT = (BM / 8) * (BN / 8);
  constexpr int LDA = BM + 4;
  __shared__ float AsT[KC][LDA];           // A transposed: [k][m]
  __shared__ float Ws[KC][BN];             // [k][n]
  int row0 = blockIdx.x * BM;
  int n0   = blockIdx.y * BN;
  int tid = threadIdx.x;
  int tx = tid % (BN / 8), ty = tid / (BN / 8);
  float acc[8][8];
#pragma unroll
  for (int i = 0; i < 8; ++i)
#pragma unroll
    for (int j = 0; j < 8; ++j) acc[i][j] = 0.f;

  for (int kc = 0; kc < K; kc += KC) {
#pragma unroll
    for (int item = tid; item < BM * (KC / 4); item += NT) {
      int r = item >> 3, f4 = item & 7;
      int grow = row0 + r;
      float4 v = (grow < NNODES) ? *(const float4*)&A[(size_t)grow * K + kc + 4 * f4]
                                 : make_float4(0.f, 0.f, 0.f, 0.f);
      AsT[4 * f4 + 0][r] = v.x;
      AsT[4 * f4 + 1][r] = v.y;
      AsT[4 * f4 + 2][r] = v.z;
      AsT[4 * f4 + 3][r] = v.w;
    }
#pragma unroll
    for (int item = tid; item < KC * (BN / 4); item += NT) {
      int k = item / (BN / 4), c4 = item % (BN / 4);
      int ccat = n0 + 4 * c4;
      const float* src = (ccat < MCOLS)
          ? &W1[(size_t)(kc + k) * MCOLS + ccat]
          : &W2[(size_t)(kc + k) * MCOLS + ccat - MCOLS];
      *(float4*)&Ws[k][4 * c4] = *(const float4*)src;
    }
    __syncthreads();
#pragma unroll 8
    for (int k = 0; k < KC; ++k) {
      float4 a0 = *(const float4*)&AsT[k][4 * ty];
      float4 a1 = *(const float4*)&AsT[k][BM / 2 + 4 * ty];
      float4 w0 = *(const float4*)&Ws[k][4 * tx];
      float4 w1 = *(const float4*)&Ws[k][BN / 2 + 4 * tx];
      float av[8] = {a0.x, a0.y, a0.z, a0.w, a1.x, a1.y, a1.z, a1.w};
      float wv[8] = {w0.x, w0.y, w0.z, w0.w, w1.x, w1.y, w1.z, w1.w};
#pragma unroll
      for (int i = 0; i < 8; ++i)
#pragma unroll
        for (int j = 0; j < 8; ++j) acc[i][j] = fmaf(av[i], wv[j], acc[i][j]);
    }
    __syncthreads();
  }
#pragma unroll
  for (int i = 0; i < 8; ++i) {
    int row = row0 + (i < 4 ? 4 * ty + i : BM / 2 + 4 * ty + (i - 4));
    if (row >= NNODES) continue;
#pragma unroll
    for (int jj = 0; jj < 2; ++jj) {
      int ccat = n0 + (jj == 0 ? 4 * tx : BN / 2 + 4 * tx);
      float4 o = make_float4(acc[i][4 * jj + 0], acc[i][4 * jj + 1],
                             acc[i][4 * jj + 2], acc[i][4 * jj + 3]);
      if (ccat < MCOLS) {
        float4 bb = *(const float4*)&b1[ccat];
        o.x += bb.x; o.y += bb.y; o.z += bb.z; o.w += bb.w;
        if (BF16G1) {
          uint2 pk;
          pk.x = (uint_t)f2bf(o.x) | ((uint_t)f2bf(o.y) << 16);
          pk.y = (uint_t)f2bf(o.z) | ((uint_t)f2bf(o.w) << 16);
          *(uint2*)((ushort_t*)G1v + (size_t)row * MCOLS + ccat) = pk;
        } else {
          *(float4*)((float*)G1v + (size_t)row * MCOLS + ccat) = o;
        }
      } else {
        float4 bb = *(const float4*)&b2[ccat - MCOLS];
        o.x += bb.x; o.y += bb.y; o.z += bb.z; o.w += bb.w;
        *(float4*)&G2[(size_t)row * MCOLS + ccat - MCOLS] = o;
      }
    }
  }
}

// ---------------- layer 1: wave/node, 16 lanes/edge (8 bf16 ch = 1x16B load), 4 edges/iter ----------------
__global__ __launch_bounds__(256) void gat1_edge(const int* __restrict__ rowptr,
                          const int* __restrict__ csrc,
                          const ushort_t* __restrict__ glb,    // bf16 table [N][128]
                          const float* __restrict__ gr,
                          const float* __restrict__ att, const float* __restrict__ bias,
                          float* __restrict__ hout) {
  int node = blockIdx.x * 4 + (threadIdx.x >> 6);
  if (node >= NNODES) return;
  int lane = threadIdx.x & 63;
  int eslot = lane >> 4;        // 4 edge slots
  int q = lane & 15;            // 16 lanes per edge; lane covers 8 channels
  int c8 = q * 8;               // head = q>>2
  float4 av0 = *(const float4*)(att + c8);
  float4 av1 = *(const float4*)(att + c8 + 4);
  float4 gr0 = *(const float4*)(gr + (size_t)node * 128 + c8);
  float4 gr1v = *(const float4*)(gr + (size_t)node * 128 + c8 + 4);
  int start = rowptr[node], end = rowptr[node + 1];
  float denom = 0.f;
  float4 A0 = make_float4(0.f, 0.f, 0.f, 0.f);
  float4 A1 = make_float4(0.f, 0.f, 0.f, 0.f);
  for (int b = start; b < end; b += 64) {
    int nb = end - b; if (nb > 64) nb = 64;
    int sidx = (lane < nb) ? csrc[b + lane] : 0;
    for (int j = 0; j < nb; j += 4) {
      bool pv = (j + eslot) < nb;
      int s = __shfl(sidx, j + eslot);
      uint4 up = *(const uint4*)(glb + (size_t)s * 128 + c8);  // 8 bf16 channels
      float4 g0, g1;
      g0.x = __uint_as_float(up.x << 16);
      g0.y = __uint_as_float(up.x & 0xffff0000u);
      g0.z = __uint_as_float(up.y << 16);
      g0.w = __uint_as_float(up.y & 0xffff0000u);
      g1.x = __uint_as_float(up.z << 16);
      g1.y = __uint_as_float(up.z & 0xffff0000u);
      g1.z = __uint_as_float(up.w << 16);
      g1.w = __uint_as_float(up.w & 0xffff0000u);
      float t, v;
      t = g0.x + gr0.x; t = fmaxf(t, NEG * t); v = av0.x * t;
      t = g0.y + gr0.y; t = fmaxf(t, NEG * t); v = fmaf(av0.y, t, v);
      t = g0.z + gr0.z; t = fmaxf(t, NEG * t); v = fmaf(av0.z, t, v);
      t = g0.w + gr0.w; t = fmaxf(t, NEG * t); v = fmaf(av0.w, t, v);
      t = g1.x + gr1v.x; t = fmaxf(t, NEG * t); v = fmaf(av1.x, t, v);
      t = g1.y + gr1v.y; t = fmaxf(t, NEG * t); v = fmaf(av1.y, t, v);
      t = g1.z + gr1v.z; t = fmaxf(t, NEG * t); v = fmaf(av1.z, t, v);
      t = g1.w + gr1v.w; t = fmaxf(t, NEG * t); v = fmaf(av1.w, t, v);
      v += __shfl_xor(v, 1); v += __shfl_xor(v, 2);   // e[head] over 4 lanes (32 ch)
      float ex = pv ? __expf(v) : 0.f;                // |e| bounded: max-free softmax
      denom += ex;
      A0.x = fmaf(ex, g0.x, A0.x); A0.y = fmaf(ex, g0.y, A0.y);
      A0.z = fmaf(ex, g0.z, A0.z); A0.w = fmaf(ex, g0.w, A0.w);
      A1.x = fmaf(ex, g1.x, A1.x); A1.y = fmaf(ex, g1.y, A1.y);
      A1.z = fmaf(ex, g1.z, A1.z); A1.w = fmaf(ex, g1.w, A1.w);
    }
  }
  denom += __shfl_xor(denom, 16); denom += __shfl_xor(denom, 32);
  A0.x += __shfl_xor(A0.x, 16); A0.x += __shfl_xor(A0.x, 32);
  A0.y += __shfl_xor(A0.y, 16); A0.y += __shfl_xor(A0.y, 32);
  A0.z += __shfl_xor(A0.z, 16); A0.z += __shfl_xor(A0.z, 32);
  A0.w += __shfl_xor(A0.w, 16); A0.w += __shfl_xor(A0.w, 32);
  A1.x += __shfl_xor(A1.x, 16); A1.x += __shfl_xor(A1.x, 32);
  A1.y += __shfl_xor(A1.y, 16); A1.y += __shfl_xor(A1.y, 32);
  A1.z += __shfl_xor(A1.z, 16); A1.z += __shfl_xor(A1.z, 32);
  A1.w += __shfl_xor(A1.w, 16); A1.w += __shfl_xor(A1.w, 32);
  float inv = 1.f / denom;
  if (eslot == 0) {
    float4 bv = *(const float4*)(bias + c8);
    float4 o;
    o.x = A0.x * inv + bv.x; o.y = A0.y * inv + bv.y;
    o.z = A0.z * inv + bv.z; o.w = A0.w * inv + bv.w;
    o.x = o.x > 0.f ? o.x : __expf(o.x) - 1.f;
    o.y = o.y > 0.f ? o.y : __expf(o.y) - 1.f;
    o.z = o.z > 0.f ? o.z : __expf(o.z) - 1.f;
    o.w = o.w > 0.f ? o.w : __expf(o.w) - 1.f;
    *(float4*)(hout + (size_t)node * 128 + c8) = o;
  } else if (eslot == 1) {
    float4 bv = *(const float4*)(bias + c8 + 4);
    float4 o;
    o.x = A1.x * inv + bv.x; o.y = A1.y * inv + bv.y;
    o.z = A1.z * inv + bv.z; o.w = A1.w * inv + bv.w;
    o.x = o.x > 0.f ? o.x : __expf(o.x) - 1.f;
    o.y = o.y > 0.f ? o.y : __expf(o.y) - 1.f;
    o.z = o.z > 0.f ? o.z : __expf(o.z) - 1.f;
    o.w = o.w > 0.f ? o.w : __expf(o.w) - 1.f;
    *(float4*)(hout + (size_t)node * 128 + c8 + 4) = o;
  }
}

// ---------------- layer 2: wave/node, 8 lanes/edge (4 ch), 8 edges/iter ----------------
__global__ __launch_bounds__(256) void gat2_edge(const int* __restrict__ rowptr,
                          const int* __restrict__ csrc,
                          const float* __restrict__ gl, const float* __restrict__ gr,
                          const float* __restrict__ att, const float* __restrict__ bias,
                          float* __restrict__ out) {
  int node = blockIdx.x * 4 + (threadIdx.x >> 6);
  if (node >= NNODES) return;
  int lane = threadIdx.x & 63;
  int eslot = lane >> 3;        // 8 edge slots
  int q = lane & 7;             // 8 lanes per edge, 4 ch each
  int c4 = q * 4;
  float4 avc = *(const float4*)(att + c4);
  float4 grd = *(const float4*)(gr + (size_t)node * 32 + c4);
  int start = rowptr[node], end = rowptr[node + 1];
  float denom = 0.f;
  float4 A = make_float4(0.f, 0.f, 0.f, 0.f);
  for (int b = start; b < end; b += 64) {
    int nb = end - b; if (nb > 64) nb = 64;
    int sidx = (lane < nb) ? csrc[b + lane] : 0;
    for (int j = 0; j < nb; j += 8) {
      bool pv = (j + eslot) < nb;
      int s = __shfl(sidx, j + eslot);
      float4 g = *(const float4*)(gl + (size_t)s * 32 + c4);
      float t, v;
      t = g.x + grd.x; t = fmaxf(t, NEG * t); v = avc.x * t;
      t = g.y + grd.y; t = fmaxf(t, NEG * t); v = fmaf(avc.y, t, v);
      t = g.z + grd.z; t = fmaxf(t, NEG * t); v = fmaf(avc.z, t, v);
      t = g.w + grd.w; t = fmaxf(t, NEG * t); v = fmaf(avc.w, t, v);
      v += __shfl_xor(v, 1); v += __shfl_xor(v, 2); v += __shfl_xor(v, 4);
      float ex = pv ? __expf(v) : 0.f;
      denom += ex;
      A.x = fmaf(ex, g.x, A.x); A.y = fmaf(ex, g.y, A.y);
      A.z = fmaf(ex, g.z, A.z); A.w = fmaf(ex, g.w, A.w);
    }
  }
  denom += __shfl_xor(denom, 8); denom += __shfl_xor(denom, 16); denom += __shfl_xor(denom, 32);
  A.x += __shfl_xor(A.x, 8); A.x += __shfl_xor(A.x, 16); A.x += __shfl_xor(A.x, 32);
  A.y += __shfl_xor(A.y, 8); A.y += __shfl_xor(A.y, 16); A.y += __shfl_xor(A.y, 32);
  A.z += __shfl_xor(A.z, 8); A.z += __shfl_xor(A.z, 16); A.z += __shfl_xor(A.z, 32);
  A.w += __shfl_xor(A.w, 8); A.w += __shfl_xor(A.w, 16); A.w += __shfl_xor(A.w, 32);
  if (eslot == 0) {
    float4 bv = *(const float4*)(bias + c4);
    float inv = 1.f / denom;
    float4 o;
    o.x = A.x * inv + bv.x; o.y = A.y * inv + bv.y;
    o.z = A.z * inv + bv.z; o.w = A.w * inv + bv.w;
    *(float4*)(out + (size_t)node * 32 + c4) = o;
  }
}

extern "C" void kernel_launch(void* const* d_in, const int* in_sizes, int n_in,
                              void* d_out, int out_size, void* d_ws, size_t ws_size,
                              hipStream_t stream) {
  const float* x     = (const float*)d_in[0];
  const int*   ei    = (const int*)  d_in[1];
  const float* Wl1   = (const float*)d_in[2];
  const float* bl1   = (const float*)d_in[3];
  const float* Wr1   = (const float*)d_in[4];
  const float* br1   = (const float*)d_in[5];
  const float* att1  = (const float*)d_in[6];
  const float* bias1 = (const float*)d_in[7];
  const float* Wl2   = (const float*)d_in[8];
  const float* bl2   = (const float*)d_in[9];
  const float* Wr2   = (const float*)d_in[10];
  const float* br2   = (const float*)d_in[11];
  const float* att2  = (const float*)d_in[12];
  const float* bias2 = (const float*)d_in[13];
  float* out = (float*)d_out;

  char* w = (char*)d_ws;
  auto carve = [&](size_t bytes) {
    char* p = w;
    w += (bytes + 255) & ~(size_t)255;
    return p;
  };
  ushort_t* gl1 = (ushort_t*)carve((size_t)NNODES * 128 * 2);   // bf16 gather table
  float* gr1 = (float*)carve((size_t)NNODES * 128 * 4);
  float* h   = (float*)carve((size_t)NNODES * 128 * 4);
  float* gl2 = (float*)carve((size_t)NNODES * 32 * 4);
  float* gr2 = (float*)carve((size_t)NNODES * 32 * 4);
  ushort_t* WtHi = (ushort_t*)carve((size_t)256 * 128 * 2);
  ushort_t* WtLo = (ushort_t*)carve((size_t)256 * 128 * 2);
  int* pcnt    = (int*)carve((size_t)NP1 * BKTS * 4);
  int* goffArr = (int*)carve((size_t)NP1 * BKTS * 4);
  int* tot     = (int*)carve((size_t)BKTS * 4);
  int* bucketStart = (int*)carve((size_t)(BKTS + 1) * 4);
  int* rowptr = (int*)carve((size_t)(NNODES + 1) * 4);
  uint_t* binned = (uint_t*)carve((size_t)ETOT * 4);
  int* csrc = (int*)carve((size_t)ETOT * 4);

  prep_w<<<128, 256, 0, stream>>>(Wl1, Wr1, WtHi, WtLo);
  coarse_hist<<<NP1, 256, 0, stream>>>(ei, pcnt);
  coarse_scan<<<BKTS, 64, 0, stream>>>(pcnt, goffArr, tot);
  bucket_scan<<<1, 256, 0, stream>>>(tot, bucketStart, rowptr);
  bin_phase1<<<NP1, 256, 0, stream>>>(ei, bucketStart, goffArr, binned);
  bin_phase2<<<BKTS, 256, 0, stream>>>(binned, bucketStart, rowptr, csrc);

  gemm1_mfma<<<(NNODES + 31) / 32, 256, 0, stream>>>(x, WtHi, WtLo, bl1, br1, gl1, gr1);
  gat1_edge<<<(NNODES + 3) / 4, 256, 0, stream>>>(rowptr, csrc, gl1, gr1, att1, bias1, h);
  gemm_tile<128, 64, 32, false><<<dim3((NNODES + 127) / 128, 1), 128, 0, stream>>>(
      h, Wl2, bl2, Wr2, br2, (void*)gl2, gr2);
  gat2_edge<<<(NNODES + 3) / 4, 256, 0, stream>>>(rowptr, csrc, gl2, gr2, att2, bias2, out);
}

// Round 15
// 262.919 us; speedup vs baseline: 1.0604x; 1.0371x over previous
//
#include <hip/hip_runtime.h>

#define NNODES 50000
#define NEDGES 800000
#define ETOT   (NNODES + NEDGES)   // 850000 (edges + self loops)
#define NEG 0.2f
#define BKTS 196                   // coarse buckets of 256 nodes (49999>>8 = 195)
#define P1E 4096                   // edges per phase-1 block
#define NP1 ((ETOT + P1E - 1) / P1E)   // 208

typedef unsigned short ushort_t;
typedef unsigned int uint_t;
typedef __attribute__((ext_vector_type(8))) short short8;   // 8 bf16 (4 VGPRs)
typedef __attribute__((ext_vector_type(4))) float f32x4;    // 4 fp32 acc

__device__ __forceinline__ ushort_t f2bf(float f) {   // RTN bf16
  uint_t u = __float_as_uint(f);
  u += 0x7FFFu + ((u >> 16) & 1u);
  return (ushort_t)(u >> 16);
}
__device__ __forceinline__ float bf2f(ushort_t h) {
  return __uint_as_float((uint_t)h << 16);
}

// ---------------- CSR build: two-level LDS counting sort (atomic-free global) ----------------
__global__ __launch_bounds__(256) void coarse_hist(const int* __restrict__ ei,
                                                   int* __restrict__ pcnt) {
  __shared__ int c[BKTS];
  for (int i = threadIdx.x; i < BKTS; i += 256) c[i] = 0;
  __syncthreads();
  int e0 = blockIdx.x * P1E;
#pragma unroll
  for (int t = 0; t < P1E / 256; ++t) {
    int i = e0 + t * 256 + (int)threadIdx.x;
    if (i < ETOT) {
      int dst = (i < NEDGES) ? ei[NEDGES + i] : (i - NEDGES);
      atomicAdd(&c[dst >> 8], 1);
    }
  }
  __syncthreads();
  for (int i = threadIdx.x; i < BKTS; i += 256)
    pcnt[i * NP1 + blockIdx.x] = c[i];
}

__global__ __launch_bounds__(64) void coarse_scan(const int* __restrict__ pcnt,
                                                  int* __restrict__ goffArr,
                                                  int* __restrict__ tot) {
  int b = blockIdx.x;
  int lane = threadIdx.x;
  int carry = 0;
  for (int k0 = 0; k0 < NP1; k0 += 64) {
    int k = k0 + lane;
    int v = (k < NP1) ? pcnt[b * NP1 + k] : 0;
    int s = v;
    for (int off = 1; off < 64; off <<= 1) {
      int u = __shfl_up(s, off);
      if (lane >= off) s += u;
    }
    if (k < NP1) goffArr[b * NP1 + k] = carry + s - v;   // exclusive
    carry += __shfl(s, 63);
  }
  if (lane == 0) tot[b] = carry;
}

__global__ __launch_bounds__(256) void bucket_scan(const int* __restrict__ tot,
                                                   int* __restrict__ bucketStart,
                                                   int* __restrict__ rowptr) {
  if (threadIdx.x == 0) {
    int r = 0;
    for (int i = 0; i < BKTS; ++i) { bucketStart[i] = r; r += tot[i]; }
    bucketStart[BKTS] = r;          // == ETOT
    rowptr[NNODES] = ETOT;
  }
}

__global__ __launch_bounds__(256) void bin_phase1(const int* __restrict__ ei,
                                                  const int* __restrict__ bucketStart,
                                                  const int* __restrict__ goffArr,
                                                  uint_t* __restrict__ binned) {
  __shared__ int cnt[BKTS], pref[BKTS], fillL[BKTS];
  __shared__ uint_t stage[P1E];
  int e0 = blockIdx.x * P1E;
  for (int i = threadIdx.x; i < BKTS; i += 256) { cnt[i] = 0; fillL[i] = 0; }
  __syncthreads();
  uint_t mypk[P1E / 256];
  int mybkt[P1E / 256];
#pragma unroll
  for (int t = 0; t < P1E / 256; ++t) {
    int i = e0 + t * 256 + (int)threadIdx.x;
    if (i < ETOT) {
      int dst = (i < NEDGES) ? ei[NEDGES + i] : (i - NEDGES);
      int src = (i < NEDGES) ? ei[i] : dst;
      int b = dst >> 8;
      mypk[t] = (uint_t)src | ((uint_t)(dst & 255) << 16) | ((uint_t)b << 24);
      mybkt[t] = b;
      atomicAdd(&cnt[b], 1);
    } else mybkt[t] = -1;
  }
  __syncthreads();
  if (threadIdx.x == 0) {
    int r = 0;
    for (int b = 0; b < BKTS; ++b) { pref[b] = r; r += cnt[b]; }
  }
  __syncthreads();
#pragma unroll
  for (int t = 0; t < P1E / 256; ++t) {
    if (mybkt[t] >= 0) {
      int p = pref[mybkt[t]] + atomicAdd(&fillL[mybkt[t]], 1);
      stage[p] = mypk[t];
    }
  }
  __syncthreads();
  int total = (e0 + P1E <= ETOT) ? P1E : (ETOT - e0);
  for (int j = threadIdx.x; j < total; j += 256) {
    uint_t pk = stage[j];
    int b = pk >> 24;
    binned[bucketStart[b] + goffArr[b * NP1 + blockIdx.x] + (j - pref[b])] = pk;
  }
}

__global__ __launch_bounds__(256) void bin_phase2(const uint_t* __restrict__ binned,
                                                  const int* __restrict__ bucketStart,
                                                  int* __restrict__ rowptr,
                                                  int* __restrict__ csrc) {
  __shared__ int cnt[256], pref[256], fillL[256];
  __shared__ int outS[8192];       // max bucket ~4700; ample
  int b = blockIdx.x;
  int base = bucketStart[b];
  int cntAll = bucketStart[b + 1] - base;
  cnt[threadIdx.x] = 0; fillL[threadIdx.x] = 0;
  __syncthreads();
  for (int j = threadIdx.x; j < cntAll; j += 256)
    atomicAdd(&cnt[(binned[base + j] >> 16) & 255], 1);
  __syncthreads();
  if (threadIdx.x == 0) {
    int r = 0;
    for (int i = 0; i < 256; ++i) { pref[i] = r; r += cnt[i]; }
  }
  __syncthreads();
  int node = b * 256 + (int)threadIdx.x;
  if (node < NNODES) rowptr[node] = base + pref[threadIdx.x];
  for (int j = threadIdx.x; j < cntAll; j += 256) {
    uint_t pk = binned[base + j];
    int d = (pk >> 16) & 255;
    int p = pref[d] + atomicAdd(&fillL[d], 1);
    outS[p] = (int)(pk & 0xFFFF);
  }
  __syncthreads();
  for (int j = threadIdx.x; j < cntAll; j += 256)
    csrc[base + j] = outS[j];
}

// ---------------- W prep: transpose + split-bf16 [n][k] ----------------
__global__ __launch_bounds__(256) void prep_w(const float* __restrict__ Wl1,
                                              const float* __restrict__ Wr1,
                                              ushort_t* __restrict__ WtHi,
                                              ushort_t* __restrict__ WtLo) {
  int k = blockIdx.x;           // 0..127
  int n = threadIdx.x;          // 0..255 (concat col)
  float w = (n < 128) ? Wl1[k * 128 + n] : Wr1[k * 128 + (n - 128)];
  ushort_t h = f2bf(w);
  WtHi[n * 128 + k] = h;
  WtLo[n * 128 + k] = f2bf(w - bf2f(h));
}

// ---------------- GEMM1 via MFMA (split-bf16 = fp32-quality); gl1+gr1 both bf16 out ----------------
__global__ __launch_bounds__(256) void gemm1_mfma(
    const float* __restrict__ x,
    const ushort_t* __restrict__ WtHi, const ushort_t* __restrict__ WtLo,
    const float* __restrict__ bl1, const float* __restrict__ br1,
    ushort_t* __restrict__ gl1, ushort_t* __restrict__ gr1) {
  constexpr int LDA = 132;
  __shared__ __align__(16) char smem[32 * 260 * 4];   // Cs overlays Ahi/Alo
  ushort_t (*Ahi)[LDA] = (ushort_t(*)[LDA])smem;
  ushort_t (*Alo)[LDA] = (ushort_t(*)[LDA])(smem + 32 * LDA * 2);
  float (*Cs)[260] = (float(*)[260])smem;
  int m0 = blockIdx.x * 32;
  int tid = threadIdx.x;
#pragma unroll
  for (int i = 0; i < 4; ++i) {
    int it = i * 256 + tid;
    int row = it >> 5, c4 = it & 31;
    int gm = m0 + row;
    float4 v = (gm < NNODES) ? *(const float4*)&x[(size_t)gm * 128 + 4 * c4]
                             : make_float4(0.f, 0.f, 0.f, 0.f);
    ushort_t h0 = f2bf(v.x), h1 = f2bf(v.y), h2 = f2bf(v.z), h3 = f2bf(v.w);
    ushort_t l0 = f2bf(v.x - bf2f(h0)), l1 = f2bf(v.y - bf2f(h1));
    ushort_t l2 = f2bf(v.z - bf2f(h2)), l3 = f2bf(v.w - bf2f(h3));
    uint2 ph, pl;
    ph.x = (uint_t)h0 | ((uint_t)h1 << 16); ph.y = (uint_t)h2 | ((uint_t)h3 << 16);
    pl.x = (uint_t)l0 | ((uint_t)l1 << 16); pl.y = (uint_t)l2 | ((uint_t)l3 << 16);
    *(uint2*)&Ahi[row][4 * c4] = ph;
    *(uint2*)&Alo[row][4 * c4] = pl;
  }
  __syncthreads();
  int wave = tid >> 6, lane = tid & 63;
  int quad = lane >> 4, nl = lane & 15;
  int nb = wave * 64;
  f32x4 acc[2][4];
#pragma unroll
  for (int tm = 0; tm < 2; ++tm)
#pragma unroll
    for (int tn = 0; tn < 4; ++tn) acc[tm][tn] = (f32x4){0.f, 0.f, 0.f, 0.f};

#pragma unroll
  for (int kc = 0; kc < 4; ++kc) {
    int klane = kc * 32 + quad * 8;
    short8 ah[2], al[2], bh[4], bl[4];
#pragma unroll
    for (int tm = 0; tm < 2; ++tm) {
      ah[tm] = *(const short8*)&Ahi[16 * tm + nl][klane];
      al[tm] = *(const short8*)&Alo[16 * tm + nl][klane];
    }
#pragma unroll
    for (int tn = 0; tn < 4; ++tn) {
      size_t wo = (size_t)(nb + 16 * tn + nl) * 128 + klane;
      bh[tn] = *(const short8*)&WtHi[wo];
      bl[tn] = *(const short8*)&WtLo[wo];
    }
#pragma unroll
    for (int tm = 0; tm < 2; ++tm)
#pragma unroll
      for (int tn = 0; tn < 4; ++tn) {
        acc[tm][tn] = __builtin_amdgcn_mfma_f32_16x16x32_bf16(ah[tm], bh[tn], acc[tm][tn], 0, 0, 0);
        acc[tm][tn] = __builtin_amdgcn_mfma_f32_16x16x32_bf16(ah[tm], bl[tn], acc[tm][tn], 0, 0, 0);
        acc[tm][tn] = __builtin_amdgcn_mfma_f32_16x16x32_bf16(al[tm], bh[tn], acc[tm][tn], 0, 0, 0);
      }
  }
  float bb[4];
#pragma unroll
  for (int tn = 0; tn < 4; ++tn) {
    int n = nb + 16 * tn + nl;
    bb[tn] = (n < 128) ? bl1[n] : br1[n - 128];
  }
  __syncthreads();   // all A-tile reads done before Cs overlays the same LDS
#pragma unroll
  for (int tm = 0; tm < 2; ++tm)
#pragma unroll
    for (int tn = 0; tn < 4; ++tn)
#pragma unroll
      for (int r = 0; r < 4; ++r)
        Cs[16 * tm + 4 * quad + r][nb + 16 * tn + nl] = acc[tm][tn][r] + bb[tn];
  __syncthreads();
#pragma unroll
  for (int i = 0; i < 2; ++i) {     // gl1 (cols 0..127, bf16)
    int it = i * 256 + tid;
    int row = it >> 4, oc = (it & 15) * 8;
    int gm = m0 + row;
    if (gm < NNODES) {
      uint4 pk;
      pk.x = (uint_t)f2bf(Cs[row][oc + 0]) | ((uint_t)f2bf(Cs[row][oc + 1]) << 16);
      pk.y = (uint_t)f2bf(Cs[row][oc + 2]) | ((uint_t)f2bf(Cs[row][oc + 3]) << 16);
      pk.z = (uint_t)f2bf(Cs[row][oc + 4]) | ((uint_t)f2bf(Cs[row][oc + 5]) << 16);
      pk.w = (uint_t)f2bf(Cs[row][oc + 6]) | ((uint_t)f2bf(Cs[row][oc + 7]) << 16);
      *(uint4*)&gl1[(size_t)gm * 128 + oc] = pk;
    }
  }
#pragma unroll
  for (int i = 0; i < 2; ++i) {     // gr1 (cols 128..255, bf16)
    int it = i * 256 + tid;
    int row = it >> 4, oc = (it & 15) * 8;
    int gm = m0 + row;
    if (gm < NNODES) {
      uint4 pk;
      pk.x = (uint_t)f2bf(Cs[row][128 + oc + 0]) | ((uint_t)f2bf(Cs[row][128 + oc + 1]) << 16);
      pk.y = (uint_t)f2bf(Cs[row][128 + oc + 2]) | ((uint_t)f2bf(Cs[row][128 + oc + 3]) << 16);
      pk.z = (uint_t)f2bf(Cs[row][128 + oc + 4]) | ((uint_t)f2bf(Cs[row][128 + oc + 5]) << 16);
      pk.w = (uint_t)f2bf(Cs[row][128 + oc + 6]) | ((uint_t)f2bf(Cs[row][128 + oc + 7]) << 16);
      *(uint4*)&gr1[(size_t)gm * 128 + oc] = pk;
    }
  }
}

// ---------------- GEMM2: bf16 h in, bf16 gl2/gr2 out (fp32 compute) ----------------
__global__ __launch_bounds__(128) void gemm2_tile(
    const ushort_t* __restrict__ A,               // h, bf16 [N][128]
    const float* __restrict__ W1, const float* __restrict__ b1,
    const float* __restrict__ W2, const float* __restrict__ b2,
    ushort_t* __restrict__ G1, ushort_t* __restrict__ G2) {
  constexpr int K = 128, KC = 32, BM = 128, BN = 64, MCOLS = 32, NT = 128;
  constexpr int LDA = BM + 4;
  __shared__ float AsT[KC][LDA];
  __shared__ float Ws[KC][BN];
  int row0 = blockIdx.x * BM;
  int tid = threadIdx.x;
  int tx = tid % (BN / 8), ty = tid / (BN / 8);
  float acc[8][8];
#pragma unroll
  for (int i = 0; i < 8; ++i)
#pragma unroll
    for (int j = 0; j < 8; ++j) acc[i][j] = 0.f;

  for (int kc = 0; kc < K; kc += KC) {
#pragma unroll
    for (int item = tid; item < BM * (KC / 4); item += NT) {
      int r = item >> 3, f4 = item & 7;
      int grow = row0 + r;
      uint2 u = (grow < NNODES)
          ? *(const uint2*)&A[(size_t)grow * K + kc + 4 * f4]
          : make_uint2(0u, 0u);
      AsT[4 * f4 + 0][r] = __uint_as_float(u.x << 16);
      AsT[4 * f4 + 1][r] = __uint_as_float(u.x & 0xffff0000u);
      AsT[4 * f4 + 2][r] = __uint_as_float(u.y << 16);
      AsT[4 * f4 + 3][r] = __uint_as_float(u.y & 0xffff0000u);
    }
#pragma unroll
    for (int item = tid; item < KC * (BN / 4); item += NT) {
      int k = item / (BN / 4), c4 = item % (BN / 4);
      int ccat = 4 * c4;
      const float* src = (ccat < MCOLS)
          ? &W1[(size_t)(kc + k) * MCOLS + ccat]
          : &W2[(size_t)(kc + k) * MCOLS + ccat - MCOLS];
      *(float4*)&Ws[k][4 * c4] = *(const float4*)src;
    }
    __syncthreads();
#pragma unroll 8
    for (int k = 0; k < KC; ++k) {
      float4 a0 = *(const float4*)&AsT[k][4 * ty];
      float4 a1 = *(const float4*)&AsT[k][BM / 2 + 4 * ty];
      float4 w0 = *(const float4*)&Ws[k][4 * tx];
      float4 w1 = *(const float4*)&Ws[k][BN / 2 + 4 * tx];
      float av[8] = {a0.x, a0.y, a0.z, a0.w, a1.x, a1.y, a1.z, a1.w};
      float wv[8] = {w0.x, w0.y, w0.z, w0.w, w1.x, w1.y, w1.z, w1.w};
#pragma unroll
      for (int i = 0; i < 8; ++i)
#pragma unroll
        for (int j = 0; j < 8; ++j) acc[i][j] = fmaf(av[i], wv[j], acc[i][j]);
    }
    __syncthreads();
  }
#pragma unroll
  for (int i = 0; i < 8; ++i) {
    int row = row0 + (i < 4 ? 4 * ty + i : BM / 2 + 4 * ty + (i - 4));
    if (row >= NNODES) continue;
#pragma unroll
    for (int jj = 0; jj < 2; ++jj) {
      int ccat = (jj == 0 ? 4 * tx : BN / 2 + 4 * tx);
      float o0 = acc[i][4 * jj + 0], o1 = acc[i][4 * jj + 1];
      float o2 = acc[i][4 * jj + 2], o3 = acc[i][4 * jj + 3];
      if (ccat < MCOLS) {
        float4 bb = *(const float4*)&b1[ccat];
        uint2 pk;
        pk.x = (uint_t)f2bf(o0 + bb.x) | ((uint_t)f2bf(o1 + bb.y) << 16);
        pk.y = (uint_t)f2bf(o2 + bb.z) | ((uint_t)f2bf(o3 + bb.w) << 16);
        *(uint2*)&G1[(size_t)row * MCOLS + ccat] = pk;
      } else {
        int c = ccat - MCOLS;
        float4 bb = *(const float4*)&b2[c];
        uint2 pk;
        pk.x = (uint_t)f2bf(o0 + bb.x) | ((uint_t)f2bf(o1 + bb.y) << 16);
        pk.y = (uint_t)f2bf(o2 + bb.z) | ((uint_t)f2bf(o3 + bb.w) << 16);
        *(uint2*)&G2[(size_t)row * MCOLS + c] = pk;
      }
    }
  }
}

// ---------------- layer 1: wave/node, 16 lanes/edge (8 bf16 ch = 1x16B load), 4 edges/iter ----------------
__global__ __launch_bounds__(256) void gat1_edge(const int* __restrict__ rowptr,
                          const int* __restrict__ csrc,
                          const ushort_t* __restrict__ glb,    // bf16 table [N][128]
                          const ushort_t* __restrict__ grb,    // bf16 [N][128]
                          const float* __restrict__ att, const float* __restrict__ bias,
                          ushort_t* __restrict__ hout) {       // bf16 [N][128]
  int node = blockIdx.x * 4 + (threadIdx.x >> 6);
  if (node >= NNODES) return;
  int lane = threadIdx.x & 63;
  int eslot = lane >> 4;        // 4 edge slots
  int q = lane & 15;            // 16 lanes per edge; lane covers 8 channels
  int c8 = q * 8;               // head = q>>2
  float4 av0 = *(const float4*)(att + c8);
  float4 av1 = *(const float4*)(att + c8 + 4);
  uint4 ug = *(const uint4*)(grb + (size_t)node * 128 + c8);
  float4 gr0, gr1v;
  gr0.x = __uint_as_float(ug.x << 16);  gr0.y = __uint_as_float(ug.x & 0xffff0000u);
  gr0.z = __uint_as_float(ug.y << 16);  gr0.w = __uint_as_float(ug.y & 0xffff0000u);
  gr1v.x = __uint_as_float(ug.z << 16); gr1v.y = __uint_as_float(ug.z & 0xffff0000u);
  gr1v.z = __uint_as_float(ug.w << 16); gr1v.w = __uint_as_float(ug.w & 0xffff0000u);
  int start = rowptr[node], end = rowptr[node + 1];
  float denom = 0.f;
  float4 A0 = make_float4(0.f, 0.f, 0.f, 0.f);
  float4 A1 = make_float4(0.f, 0.f, 0.f, 0.f);
  for (int b = start; b < end; b += 64) {
    int nb = end - b; if (nb > 64) nb = 64;
    int sidx = (lane < nb) ? csrc[b + lane] : 0;
    for (int j = 0; j < nb; j += 4) {
      bool pv = (j + eslot) < nb;
      int s = __shfl(sidx, j + eslot);
      uint4 up = *(const uint4*)(glb + (size_t)s * 128 + c8);  // 8 bf16 channels
      float4 g0, g1;
      g0.x = __uint_as_float(up.x << 16);
      g0.y = __uint_as_float(up.x & 0xffff0000u);
      g0.z = __uint_as_float(up.y << 16);
      g0.w = __uint_as_float(up.y & 0xffff0000u);
      g1.x = __uint_as_float(up.z << 16);
      g1.y = __uint_as_float(up.z & 0xffff0000u);
      g1.z = __uint_as_float(up.w << 16);
      g1.w = __uint_as_float(up.w & 0xffff0000u);
      float t, v;
      t = g0.x + gr0.x; t = fmaxf(t, NEG * t); v = av0.x * t;
      t = g0.y + gr0.y; t = fmaxf(t, NEG * t); v = fmaf(av0.y, t, v);
      t = g0.z + gr0.z; t = fmaxf(t, NEG * t); v = fmaf(av0.z, t, v);
      t = g0.w + gr0.w; t = fmaxf(t, NEG * t); v = fmaf(av0.w, t, v);
      t = g1.x + gr1v.x; t = fmaxf(t, NEG * t); v = fmaf(av1.x, t, v);
      t = g1.y + gr1v.y; t = fmaxf(t, NEG * t); v = fmaf(av1.y, t, v);
      t = g1.z + gr1v.z; t = fmaxf(t, NEG * t); v = fmaf(av1.z, t, v);
      t = g1.w + gr1v.w; t = fmaxf(t, NEG * t); v = fmaf(av1.w, t, v);
      v += __shfl_xor(v, 1); v += __shfl_xor(v, 2);   // e[head] over 4 lanes (32 ch)
      float ex = pv ? __expf(v) : 0.f;                // |e| bounded: max-free softmax
      denom += ex;
      A0.x = fmaf(ex, g0.x, A0.x); A0.y = fmaf(ex, g0.y, A0.y);
      A0.z = fmaf(ex, g0.z, A0.z); A0.w = fmaf(ex, g0.w, A0.w);
      A1.x = fmaf(ex, g1.x, A1.x); A1.y = fmaf(ex, g1.y, A1.y);
      A1.z = fmaf(ex, g1.z, A1.z); A1.w = fmaf(ex, g1.w, A1.w);
    }
  }
  denom += __shfl_xor(denom, 16); denom += __shfl_xor(denom, 32);
  A0.x += __shfl_xor(A0.x, 16); A0.x += __shfl_xor(A0.x, 32);
  A0.y += __shfl_xor(A0.y, 16); A0.y += __shfl_xor(A0.y, 32);
  A0.z += __shfl_xor(A0.z, 16); A0.z += __shfl_xor(A0.z, 32);
  A0.w += __shfl_xor(A0.w, 16); A0.w += __shfl_xor(A0.w, 32);
  A1.x += __shfl_xor(A1.x, 16); A1.x += __shfl_xor(A1.x, 32);
  A1.y += __shfl_xor(A1.y, 16); A1.y += __shfl_xor(A1.y, 32);
  A1.z += __shfl_xor(A1.z, 16); A1.z += __shfl_xor(A1.z, 32);
  A1.w += __shfl_xor(A1.w, 16); A1.w += __shfl_xor(A1.w, 32);
  float inv = 1.f / denom;
  if (eslot == 0) {
    float4 bv = *(const float4*)(bias + c8);
    float o0 = A0.x * inv + bv.x, o1 = A0.y * inv + bv.y;
    float o2 = A0.z * inv + bv.z, o3 = A0.w * inv + bv.w;
    o0 = o0 > 0.f ? o0 : __expf(o0) - 1.f;   // ELU
    o1 = o1 > 0.f ? o1 : __expf(o1) - 1.f;
    o2 = o2 > 0.f ? o2 : __expf(o2) - 1.f;
    o3 = o3 > 0.f ? o3 : __expf(o3) - 1.f;
    uint2 pk;
    pk.x = (uint_t)f2bf(o0) | ((uint_t)f2bf(o1) << 16);
    pk.y = (uint_t)f2bf(o2) | ((uint_t)f2bf(o3) << 16);
    *(uint2*)&hout[(size_t)node * 128 + c8] = pk;
  } else if (eslot == 1) {
    float4 bv = *(const float4*)(bias + c8 + 4);
    float o0 = A1.x * inv + bv.x, o1 = A1.y * inv + bv.y;
    float o2 = A1.z * inv + bv.z, o3 = A1.w * inv + bv.w;
    o0 = o0 > 0.f ? o0 : __expf(o0) - 1.f;
    o1 = o1 > 0.f ? o1 : __expf(o1) - 1.f;
    o2 = o2 > 0.f ? o2 : __expf(o2) - 1.f;
    o3 = o3 > 0.f ? o3 : __expf(o3) - 1.f;
    uint2 pk;
    pk.x = (uint_t)f2bf(o0) | ((uint_t)f2bf(o1) << 16);
    pk.y = (uint_t)f2bf(o2) | ((uint_t)f2bf(o3) << 16);
    *(uint2*)&hout[(size_t)node * 128 + c8 + 4] = pk;
  }
}

// ---------------- layer 2: wave/node, 8 lanes/edge (4 ch), 8 edges/iter; bf16 tables ----------------
__global__ __launch_bounds__(256) void gat2_edge(const int* __restrict__ rowptr,
                          const int* __restrict__ csrc,
                          const ushort_t* __restrict__ gl, const ushort_t* __restrict__ gr,
                          const float* __restrict__ att, const float* __restrict__ bias,
                          float* __restrict__ out) {
  int node = blockIdx.x * 4 + (threadIdx.x >> 6);
  if (node >= NNODES) return;
  int lane = threadIdx.x & 63;
  int eslot = lane >> 3;        // 8 edge slots
  int q = lane & 7;             // 8 lanes per edge, 4 ch each
  int c4 = q * 4;
  float4 avc = *(const float4*)(att + c4);
  uint2 ugr = *(const uint2*)(gr + (size_t)node * 32 + c4);
  float4 grd;
  grd.x = __uint_as_float(ugr.x << 16); grd.y = __uint_as_float(ugr.x & 0xffff0000u);
  grd.z = __uint_as_float(ugr.y << 16); grd.w = __uint_as_float(ugr.y & 0xffff0000u);
  int start = rowptr[node], end = rowptr[node + 1];
  float denom = 0.f;
  float4 A = make_float4(0.f, 0.f, 0.f, 0.f);
  for (int b = start; b < end; b += 64) {
    int nb = end - b; if (nb > 64) nb = 64;
    int sidx = (lane < nb) ? csrc[b + lane] : 0;
    for (int j = 0; j < nb; j += 8) {
      bool pv = (j + eslot) < nb;
      int s = __shfl(sidx, j + eslot);
      uint2 ug = *(const uint2*)(gl + (size_t)s * 32 + c4);
      float4 g;
      g.x = __uint_as_float(ug.x << 16); g.y = __uint_as_float(ug.x & 0xffff0000u);
      g.z = __uint_as_float(ug.y << 16); g.w = __uint_as_float(ug.y & 0xffff0000u);
      float t, v;
      t = g.x + grd.x; t = fmaxf(t, NEG * t); v = avc.x * t;
      t = g.y + grd.y; t = fmaxf(t, NEG * t); v = fmaf(avc.y, t, v);
      t = g.z + grd.z; t = fmaxf(t, NEG * t); v = fmaf(avc.z, t, v);
      t = g.w + grd.w; t = fmaxf(t, NEG * t); v = fmaf(avc.w, t, v);
      v += __shfl_xor(v, 1); v += __shfl_xor(v, 2); v += __shfl_xor(v, 4);
      float ex = pv ? __expf(v) : 0.f;
      denom += ex;
      A.x = fmaf(ex, g.x, A.x); A.y = fmaf(ex, g.y, A.y);
      A.z = fmaf(ex, g.z, A.z); A.w = fmaf(ex, g.w, A.w);
    }
  }
  denom += __shfl_xor(denom, 8); denom += __shfl_xor(denom, 16); denom += __shfl_xor(denom, 32);
  A.x += __shfl_xor(A.x, 8); A.x += __shfl_xor(A.x, 16); A.x += __shfl_xor(A.x, 32);
  A.y += __shfl_xor(A.y, 8); A.y += __shfl_xor(A.y, 16); A.y += __shfl_xor(A.y, 32);
  A.z += __shfl_xor(A.z, 8); A.z += __shfl_xor(A.z, 16); A.z += __shfl_xor(A.z, 32);
  A.w += __shfl_xor(A.w, 8); A.w += __shfl_xor(A.w, 16); A.w += __shfl_xor(A.w, 32);
  if (eslot == 0) {
    float4 bv = *(const float4*)(bias + c4);
    float inv = 1.f / denom;
    float4 o;
    o.x = A.x * inv + bv.x; o.y = A.y * inv + bv.y;
    o.z = A.z * inv + bv.z; o.w = A.w * inv + bv.w;
    *(float4*)(out + (size_t)node * 32 + c4) = o;
  }
}

extern "C" void kernel_launch(void* const* d_in, const int* in_sizes, int n_in,
                              void* d_out, int out_size, void* d_ws, size_t ws_size,
                              hipStream_t stream) {
  const float* x     = (const float*)d_in[0];
  const int*   ei    = (const int*)  d_in[1];
  const float* Wl1   = (const float*)d_in[2];
  const float* bl1   = (const float*)d_in[3];
  const float* Wr1   = (const float*)d_in[4];
  const float* br1   = (const float*)d_in[5];
  const float* att1  = (const float*)d_in[6];
  const float* bias1 = (const float*)d_in[7];
  const float* Wl2   = (const float*)d_in[8];
  const float* bl2   = (const float*)d_in[9];
  const float* Wr2   = (const float*)d_in[10];
  const float* br2   = (const float*)d_in[11];
  const float* att2  = (const float*)d_in[12];
  const float* bias2 = (const float*)d_in[13];
  float* out = (float*)d_out;

  char* w = (char*)d_ws;
  auto carve = [&](size_t bytes) {
    char* p = w;
    w += (bytes + 255) & ~(size_t)255;
    return p;
  };
  ushort_t* gl1 = (ushort_t*)carve((size_t)NNODES * 128 * 2);   // bf16 gather table
  ushort_t* gr1 = (ushort_t*)carve((size_t)NNODES * 128 * 2);   // bf16
  ushort_t* h   = (ushort_t*)carve((size_t)NNODES * 128 * 2);   // bf16
  ushort_t* gl2 = (ushort_t*)carve((size_t)NNODES * 32 * 2);    // bf16 (fits XCD L2)
  ushort_t* gr2 = (ushort_t*)carve((size_t)NNODES * 32 * 2);    // bf16
  ushort_t* WtHi = (ushort_t*)carve((size_t)256 * 128 * 2);
  ushort_t* WtLo = (ushort_t*)carve((size_t)256 * 128 * 2);
  int* pcnt    = (int*)carve((size_t)NP1 * BKTS * 4);
  int* goffArr = (int*)carve((size_t)NP1 * BKTS * 4);
  int* tot     = (int*)carve((size_t)BKTS * 4);
  int* bucketStart = (int*)carve((size_t)(BKTS + 1) * 4);
  int* rowptr = (int*)carve((size_t)(NNODES + 1) * 4);
  uint_t* binned = (uint_t*)carve((size_t)ETOT * 4);
  int* csrc = (int*)carve((size_t)ETOT * 4);

  prep_w<<<128, 256, 0, stream>>>(Wl1, Wr1, WtHi, WtLo);
  coarse_hist<<<NP1, 256, 0, stream>>>(ei, pcnt);
  coarse_scan<<<BKTS, 64, 0, stream>>>(pcnt, goffArr, tot);
  bucket_scan<<<1, 256, 0, stream>>>(tot, bucketStart, rowptr);
  bin_phase1<<<NP1, 256, 0, stream>>>(ei, bucketStart, goffArr, binned);
  bin_phase2<<<BKTS, 256, 0, stream>>>(binned, bucketStart, rowptr, csrc);

  gemm1_mfma<<<(NNODES + 31) / 32, 256, 0, stream>>>(x, WtHi, WtLo, bl1, br1, gl1, gr1);
  gat1_edge<<<(NNODES + 3) / 4, 256, 0, stream>>>(rowptr, csrc, gl1, gr1, att1, bias1, h);
  gemm2_tile<<<(NNODES + 127) / 128, 128, 0, stream>>>(h, Wl2, bl2, Wr2, br2, gl2, gr2);
  gat2_edge<<<(NNODES + 3) / 4, 256, 0, stream>>>(rowptr, csrc, gl2, gr2, att2, bias2, out);
}